// Round 7
// baseline (82.811 us; speedup 1.0000x reference)
//
#include <hip/hip_runtime.h>

// B=8, T=16, H=512, W=512
#define HH 512
#define WW 512
#define TT 16
#define NR 10         // staged img rows: clamp(ip-4 .. ip+5); LDS = 20480 B exactly
#define OFF 4

typedef float vf4 __attribute__((ext_vector_type(4)));
typedef float vf2 __attribute__((ext_vector_type(2)));

__device__ __forceinline__ float warp_px(const float* __restrict__ lds_,
                                         const float* __restrict__ im,
                                         int ip, float fi, float fj,
                                         float ux, float uy) {
    float si = fi - ux;
    float sj = fj - uy;
    int i0 = (int)floorf(si);
    int j0 = (int)floorf(sj);
    i0 = min(max(i0, 0), HH - 1);
    j0 = min(max(j0, 0), WW - 1);
    int i1 = min(i0 + 1, HH - 1);
    // fractional weights from CLIPPED corners (matches reference)
    float di = si - (float)i0;
    float dj = sj - (float)j0;
    int s0 = i0 - ip + OFF;
    int s1 = i1 - ip + OFF;
    float f00, f01, f10, f11;
    if (((unsigned)s0 < NR) & ((unsigned)s1 < NR)) {
        // fast path: read (jb, jb+1) as one ds_read2_b32 per row.
        // jb = min(j0, 510) keeps the +1 read in-bounds; when j0==511
        // (so j1==j0==511) select b as f00. Max index = s*512+511 < 5120.
        int jb = min(j0, WW - 2);
        bool edge = (j0 == WW - 1);
        const float* p0 = lds_ + s0 * WW + jb;
        const float* p1 = lds_ + s1 * WW + jb;
        float a0 = p0[0], b0 = p0[1];
        float a1 = p1[0], b1 = p1[1];
        f00 = edge ? b0 : a0;  f01 = b0;
        f10 = edge ? b1 : a1;  f11 = b1;
    } else {
        // exactness fallback: direct global gather (P ~ 3e-5 per pixel)
        int j1 = min(j0 + 1, WW - 1);
        f00 = im[i0 * WW + j0];
        f01 = im[i0 * WW + j1];
        f10 = im[i1 * WW + j0];
        f11 = im[i1 * WW + j1];
    }
    float f0 = f00 + (f01 - f00) * dj;
    float f1 = f10 + (f11 - f10) * dj;
    return f0 + (f1 - f0) * di;
}

__global__ __launch_bounds__(256, 8) void SpatialWarp_kernel(
    const float* __restrict__ img,   // (B,H,W)
    const float* __restrict__ U,     // (B,T,H,W,2)
    float* __restrict__ out)         // (B,T,H,W)
{
    __shared__ float lds[NR * WW];             // 20480 B -> 8 blocks/CU

    int bid = blockIdx.x;                      // = b*256 + row-pair
    int b  = bid >> 8;
    int ip = (bid & 255) << 1;                 // base output row (even)
    const float* im = img + (size_t)b * (HH * WW);

    // thread k owns cols {k, k+256} on rows {ip, ip+1}: lane->col stride 1
    int c = threadIdx.x;
    float fc0 = (float)c, fc1 = (float)(c + 256);
    float fi0 = (float)ip, fi1 = (float)(ip + 1);

    const vf2* Uv = reinterpret_cast<const vf2*>(U);  // one vf2 per pixel
    size_t ubase = (((size_t)b * TT) * HH + ip) * WW; // vf2 units, t=0
    size_t ustep = (size_t)HH * WW;                   // per-t stride (vf2 units)

    // prologue: t=0 U (overlaps staging)
    vf2 u00 = __builtin_nontemporal_load(Uv + ubase + c);
    vf2 u01 = __builtin_nontemporal_load(Uv + ubase + c + 256);
    vf2 u10 = __builtin_nontemporal_load(Uv + ubase + WW + c);
    vf2 u11 = __builtin_nontemporal_load(Uv + ubase + WW + c + 256);

    // stage img rows clamp(ip-OFF .. ip-OFF+NR-1) into LDS (vec4, coalesced)
    for (int idx = threadIdx.x; idx < NR * (WW / 4); idx += 256) {
        int s = idx >> 7;            // / 128 vf4-per-row
        int cc = idx & 127;
        int r = min(max(ip - OFF + s, 0), HH - 1);
        reinterpret_cast<vf4*>(lds)[idx] =
            reinterpret_cast<const vf4*>(im + (size_t)r * WW)[cc];
    }
    __syncthreads();

#pragma unroll
    for (int t = 0; t < TT; ++t) {
        vf2 n00, n01, n10, n11;
        if (t < TT - 1) {
            size_t un = ubase + (size_t)(t + 1) * ustep;
            n00 = __builtin_nontemporal_load(Uv + un + c);
            n01 = __builtin_nontemporal_load(Uv + un + c + 256);
            n10 = __builtin_nontemporal_load(Uv + un + WW + c);
            n11 = __builtin_nontemporal_load(Uv + un + WW + c + 256);
        }
        float r00 = warp_px(lds, im, ip, fi0, fc0, u00.x, u00.y);
        float r01 = warp_px(lds, im, ip, fi0, fc1, u01.x, u01.y);
        float r10 = warp_px(lds, im, ip, fi1, fc0, u10.x, u10.y);
        float r11 = warp_px(lds, im, ip, fi1, fc1, u11.x, u11.y);

        size_t obase = (((size_t)b * TT + t) * HH + ip) * WW;
        __builtin_nontemporal_store(r00, out + obase + c);
        __builtin_nontemporal_store(r01, out + obase + c + 256);
        __builtin_nontemporal_store(r10, out + obase + WW + c);
        __builtin_nontemporal_store(r11, out + obase + WW + c + 256);

        u00 = n00; u01 = n01; u10 = n10; u11 = n11;
    }
}

extern "C" void kernel_launch(void* const* d_in, const int* in_sizes, int n_in,
                              void* d_out, int out_size, void* d_ws, size_t ws_size,
                              hipStream_t stream) {
    const float* img = (const float*)d_in[0];   // (8,512,512) fp32
    const float* U   = (const float*)d_in[1];   // (8,16,512,512,2) fp32
    float* out = (float*)d_out;                 // (8,16,512,512) fp32

    dim3 block(256);
    dim3 grid(8 * (HH / 2));                    // 2048 blocks: one per (b, row-pair)
    hipLaunchKernelGGL(SpatialWarp_kernel, grid, block, 0, stream,
                       img, U, out);
}